// Round 10
// baseline (117.795 us; speedup 1.0000x reference)
//
#include <hip/hip_runtime.h>
#include <math.h>

// Problem constants (fixed by setup_inputs shapes).
constexpr int Bc  = 8;
constexpr int Tc  = 4096;
constexpr int HLc = 8;
constexpr int Dc  = 128;
constexpr int Sc  = 4096;
constexpr int TBc = 64;   // Tb = T / bs
constexpr int BSc = 64;   // sparse_block_size

// Output offsets (float elements) in concatenated d_out, in return order.
constexpr long long O_KC   = 0LL;
constexpr long long O_VC   = 33554432LL;   // + B*T*Hl*D
constexpr long long O_VNT  = 67108864LL;   // + B*T*Hl*D
constexpr long long O_KSUM = 67371008LL;   // + B*T*Hl
constexpr long long O_CNT  = 67895296LL;   // + B*Tb*Hl*D
constexpr long long O_VNB  = 67895808LL;   // + B*Tb
constexpr long long O_PRE  = 67899904LL;   // + B*Tb*Hl

typedef float f4 __attribute__((ext_vector_type(4)));
typedef int   i4 __attribute__((ext_vector_type(4)));

__device__ inline f4 ntload4(const float* p) {
    return __builtin_nontemporal_load(reinterpret_cast<const f4*>(p));
}
__device__ inline void ntstore4(float* p, f4 v) {
    __builtin_nontemporal_store(v, reinterpret_cast<f4*>(p));
}
__device__ inline f4 ld4(const float* p) {
    return *reinterpret_cast<const f4*>(p);
}

// One 256-thread WG per (b, tb, dq). Copy work is TWO sequential loops
// (K then V): since WGs progress ~in lockstep, the chip sees ~2 HBM
// streams at a time (the 6.29 TB/s copy-ubench shape) instead of 4.
// NT loads/stores throughout (R8: removing nt = +15%). Prep (inverse
// map / count / maxpos) per-WG from pos[] via int4 loads (L2-resident).
__global__ __launch_bounds__(256) void k_main(
    const float* __restrict__ kc_old, const float* __restrict__ vc_old,
    const float* __restrict__ vnt_old, const float* __restrict__ ksum_old,
    const int* __restrict__ kcnt_old, const float* __restrict__ vnb_old,
    const float* __restrict__ kb, const float* __restrict__ vb,
    const float* __restrict__ vnorm, const int* __restrict__ pos,
    float* __restrict__ out)
{
    const int wg  = blockIdx.x;
    const int dq  = wg & 3;          // d-quarter 0..3
    const int tb  = (wg >> 2) & 63;
    const int b   = wg >> 8;
    const int tid = threadIdx.x;
    const int qp  = tid >> 6;        // row phase 0..3 (uniform per wave)
    const int sl  = tid & 63;        // float4 slot within quarter (0..63)

    __shared__ int   inv_l[BSc];
    __shared__ int   cnt_l;
    __shared__ int   maxp_l;
    __shared__ f4    red4[256];
    __shared__ float vn_l[BSc * HLc];

    if (tid < BSc) inv_l[tid] = -1;
    if (tid == 0) { cnt_l = 0; maxp_l = -1; }
    __syncthreads();

    // Per-WG prep scan over pos[] (16 KB, L2-resident), int4-vectorized.
    {
        const int base = tb * BSc;
        const i4* pos4 = reinterpret_cast<const i4*>(pos);
        int lmax = -1, lcnt = 0;
        #pragma unroll
        for (int j = 0; j < Sc / (256 * 4); ++j) {
            const int idx = tid + j * 256;        // int4 index
            const i4 pv  = pos4[idx];
            #pragma unroll
            for (int e = 0; e < 4; ++e) {
                const int pp = pv[e];
                lmax = max(lmax, pp);
                if (pp >= base && pp < base + BSc) {
                    atomicMax(&inv_l[pp - base], idx * 4 + e);  // last wins
                    ++lcnt;
                }
            }
        }
        if (dq == 0) {                // only dq0 WGs write counts
            #pragma unroll
            for (int off = 32; off >= 1; off >>= 1)
                lcnt += __shfl_xor(lcnt, off);
            if ((tid & 63) == 0) atomicAdd(&cnt_l, lcnt);
        }
        if (wg == 0) {                // only WG 0 needs max(pos)
            #pragma unroll
            for (int off = 32; off >= 1; off >>= 1)
                lmax = max(lmax, __shfl_xor(lmax, off));
            if ((tid & 63) == 0) atomicMax(&maxp_l, lmax);
        }
    }
    __syncthreads();

    constexpr int ROW = HLc * Dc;                    // 1024 floats
    const int qoff    = dq * 256;                    // quarter offset, floats
    const int dstBase = (b * Tc + tb * BSc) * ROW + qoff;
    const int srcBase = b * Sc * ROW + qoff;

    float* const okc = out + O_KC;
    float* const ovc = out + O_VC;

    // ---- K phase: 1 read stream + 1 write stream ----
    f4 ksum = (f4){0.f, 0.f, 0.f, 0.f};
    #pragma unroll
    for (int i = 0; i < 16; ++i) {
        const int r = i * 4 + qp;                    // row in block 0..63
        const int s = __builtin_amdgcn_readfirstlane(inv_l[r]);
        const int d = dstBase + r * ROW + sl * 4;
        f4 kv;
        if (s >= 0) {
            kv = ntload4(kb + srcBase + s * ROW + sl * 4);
            ksum += kv;
        } else {
            kv = ntload4(kc_old + d);
        }
        ntstore4(okc + d, kv);
    }

    // ---- V phase: 1 read stream + 1 write stream ----
    #pragma unroll
    for (int i = 0; i < 16; ++i) {
        const int r = i * 4 + qp;
        const int s = __builtin_amdgcn_readfirstlane(inv_l[r]);
        const int d = dstBase + r * ROW + sl * 4;
        f4 vv;
        if (s >= 0) {
            vv = ntload4(vb + srcBase + s * ROW + sl * 4);
        } else {
            vv = ntload4(vc_old + d);
        }
        ntstore4(ovc + d, vv);
    }
    red4[tid] = ksum;

    // v_norm_tok (dq==0 WGs only): 512 contiguous floats, coalesced;
    // stash incoming values in LDS for the per-h max.
    if (dq == 0) {
        #pragma unroll
        for (int j = 0; j < 2; ++j) {
            const int idx = tid + j * 256;           // 0..511
            const int tl = idx >> 3, h = idx & 7;
            const int s  = inv_l[tl];
            const int di = (b * Tc + tb * BSc + tl) * HLc + h;
            float vn, vm;
            if (s >= 0) {
                vn = vnorm[(b * Sc + s) * HLc + h];
                vm = vn;
            } else {
                vn = vnt_old[di];
                vm = -INFINITY;
            }
            out[O_VNT + di] = vn;
            vn_l[idx] = vm;
        }
    }
    __syncthreads();

    // k_sum_blk (this quarter): reduce 4 row-phase partials per slot.
    if (qp == 0) {
        f4 tot = red4[sl] + red4[64 + sl] + red4[128 + sl] + red4[192 + sl];
        const int o = (b * TBc + tb) * ROW + qoff + sl * 4;
        f4 old = ld4(ksum_old + o);
        ntstore4(out + O_KSUM + o, old + tot);
    }

    // v_norm_blk: per-h running max (dq==0 only).
    if (dq == 0 && tid < HLc) {
        float m = vnb_old[(b * TBc + tb) * HLc + tid];
        #pragma unroll
        for (int t = 0; t < BSc; ++t) m = fmaxf(m, vn_l[t * HLc + tid]);
        out[O_VNB + (b * TBc + tb) * HLc + tid] = m;
    }

    // counts + prefill_len (d_out read back as float32: write values).
    if (dq == 0 && tid == 0) {
        out[O_CNT + b * TBc + tb] = (float)(kcnt_old[b * TBc + tb] + cnt_l);
        if (wg == 0) out[O_PRE] = (float)(maxp_l + 1);
    }
}

extern "C" void kernel_launch(void* const* d_in, const int* in_sizes, int n_in,
                              void* d_out, int out_size, void* d_ws, size_t ws_size,
                              hipStream_t stream) {
    const float* kc_old   = (const float*)d_in[0];
    const float* vc_old   = (const float*)d_in[1];
    const float* vnt_old  = (const float*)d_in[2];
    const float* ksum_old = (const float*)d_in[3];
    const int*   kcnt_old = (const int*)d_in[4];
    const float* vnb_old  = (const float*)d_in[5];
    const int*   pos      = (const int*)d_in[6];
    const float* kb       = (const float*)d_in[7];
    const float* vb       = (const float*)d_in[8];
    const float* vnorm    = (const float*)d_in[9];
    float* out = (float*)d_out;

    k_main<<<Bc * TBc * 4, 256, 0, stream>>>(kc_old, vc_old, vnt_old,
                                             ksum_old, kcnt_old, vnb_old,
                                             kb, vb, vnorm, pos, out);
}

// Round 11
// 88.200 us; speedup vs baseline: 1.3355x; 1.3355x over previous
//
#include <hip/hip_runtime.h>
#include <math.h>

// Problem constants (fixed by setup_inputs shapes).
constexpr int Bc  = 8;
constexpr int Tc  = 4096;
constexpr int HLc = 8;
constexpr int Dc  = 128;
constexpr int Sc  = 4096;
constexpr int TBc = 64;   // Tb = T / bs
constexpr int BSc = 64;   // sparse_block_size

// Output offsets (float elements) in concatenated d_out, in return order.
constexpr long long O_KC   = 0LL;
constexpr long long O_VC   = 33554432LL;   // + B*T*Hl*D
constexpr long long O_VNT  = 67108864LL;   // + B*T*Hl*D
constexpr long long O_KSUM = 67371008LL;   // + B*T*Hl
constexpr long long O_CNT  = 67895296LL;   // + B*Tb*Hl*D
constexpr long long O_VNB  = 67895808LL;   // + B*Tb
constexpr long long O_PRE  = 67899904LL;   // + B*Tb*Hl

typedef float f4 __attribute__((ext_vector_type(4)));

__device__ inline f4 ntload4(const float* p) {
    return __builtin_nontemporal_load(reinterpret_cast<const f4*>(p));
}
__device__ inline void st4(float* p, f4 v) {
    *reinterpret_cast<f4*>(p) = v;
}
__device__ inline f4 ld4(const float* p) {
    return *reinterpret_cast<const f4*>(p);
}

// R6 structure (best: 106.16 us) with ONE change: cache stores are plain
// (L2 write-back buffered) instead of non-temporal; loads stay NT.
// Rationale: harness fill kernels sustain 6.85-7.0 TB/s with plain
// stores; R8 (plain loads AND stores) regressed, but the load side
// (268 MB streaming reads thrashing L2) plausibly caused all of it.
__global__ __launch_bounds__(1024) void k_main(
    const float* __restrict__ kc_old, const float* __restrict__ vc_old,
    const float* __restrict__ vnt_old, const float* __restrict__ ksum_old,
    const int* __restrict__ kcnt_old, const float* __restrict__ vnb_old,
    const float* __restrict__ kb, const float* __restrict__ vb,
    const float* __restrict__ vnorm, const int* __restrict__ pos,
    float* __restrict__ out)
{
    const int wg  = blockIdx.x;
    const int tb  = wg % TBc;
    const int b   = wg / TBc;
    const int tid = threadIdx.x;
    const int q   = tid >> 8;     // t-phase 0..3 (uniform per 64-lane wave)
    const int p   = tid & 255;    // float4 slot within the 1024-float row

    __shared__ int   inv_l[BSc];
    __shared__ int   cnt_l;
    __shared__ int   maxp_l;
    __shared__ f4    red4[1024];
    __shared__ float vn_l[BSc * HLc];

    if (tid < BSc) inv_l[tid] = -1;
    if (tid == 0) { cnt_l = 0; maxp_l = -1; }
    __syncthreads();

    // Per-WG prep scan over pos[] (uniform across WGs -> cache-resident).
    {
        const int base = tb * BSc;
        int lmax = -1;
        #pragma unroll
        for (int j = 0; j < Sc / 1024; ++j) {
            const int s  = tid + j * 1024;
            const int pp = pos[s];
            lmax = max(lmax, pp);
            if (pp >= base && pp < base + BSc) {
                atomicMax(&inv_l[pp - base], s);   // last-write-wins on dups
                atomicAdd(&cnt_l, 1);
            }
        }
        if (wg == 0) {   // only WG 0 needs max(pos) for prefill_len
            #pragma unroll
            for (int off = 32; off >= 1; off >>= 1)
                lmax = max(lmax, __shfl_xor(lmax, off));
            if ((tid & 63) == 0) atomicMax(&maxp_l, lmax);
        }
    }
    __syncthreads();

    constexpr int ROW = HLc * Dc;                    // 1024
    const int dstBase = (b * Tc + tb * BSc) * ROW;   // fits int
    const int srcBase = b * Sc * ROW;

    float* const okc = out + O_KC;
    float* const ovc = out + O_VC;

    f4 ksum = (f4){0.f, 0.f, 0.f, 0.f};
    #pragma unroll
    for (int i = 0; i < 16; ++i) {
        const int r = i * 4 + q;                         // row in block 0..63
        // inv_l[r] is wave-uniform: scalar branch + SGPR-side base.
        const int s = __builtin_amdgcn_readfirstlane(inv_l[r]);
        const int dst = dstBase + r * ROW + p * 4;
        f4 kv, vv;
        if (s >= 0) {
            const int src = srcBase + s * ROW + p * 4;
            kv = ntload4(kb + src);
            vv = ntload4(vb + src);
            ksum += kv;
        } else {
            kv = ntload4(kc_old + dst);
            vv = ntload4(vc_old + dst);
        }
        st4(okc + dst, kv);
        st4(ovc + dst, vv);
    }

    // v_norm_tok: 512 contiguous floats per WG, fully coalesced; stash
    // incoming values in LDS for the per-h max.
    if (tid < BSc * HLc) {
        const int tl = tid >> 3, h = tid & 7;
        const int s  = inv_l[tl];
        const int di = (b * Tc + tb * BSc + tl) * HLc + h;
        float vn, vm;
        if (s >= 0) {
            vn = vnorm[(b * Sc + s) * HLc + h];
            vm = vn;
        } else {
            vn = vnt_old[di];
            vm = -INFINITY;
        }
        out[O_VNT + di] = vn;
        vn_l[tid] = vm;
    }
    red4[tid] = ksum;
    __syncthreads();

    // k_sum_blk: reduce 4 t-phase partials per slot, add old, write float4.
    if (q == 0) {
        f4 a = red4[p], c = red4[256 + p], d = red4[512 + p],
           e = red4[768 + p];
        const int o = (b * TBc + tb) * ROW + p * 4;
        f4 old = ld4(ksum_old + o);
        f4 tot = old + a + c + d + e;
        st4(out + O_KSUM + o, tot);
    }

    // v_norm_blk: per-h running max.
    if (tid < HLc) {
        float m = vnb_old[(b * TBc + tb) * HLc + tid];
        #pragma unroll
        for (int t = 0; t < BSc; ++t) m = fmaxf(m, vn_l[t * HLc + tid]);
        out[O_VNB + (b * TBc + tb) * HLc + tid] = m;
    }

    // counts + prefill_len (d_out read back as float32: write values).
    if (tid == 0) {
        out[O_CNT + b * TBc + tb] = (float)(kcnt_old[b * TBc + tb] + cnt_l);
        if (wg == 0) out[O_PRE] = (float)(maxp_l + 1);
    }
}

extern "C" void kernel_launch(void* const* d_in, const int* in_sizes, int n_in,
                              void* d_out, int out_size, void* d_ws, size_t ws_size,
                              hipStream_t stream) {
    const float* kc_old   = (const float*)d_in[0];
    const float* vc_old   = (const float*)d_in[1];
    const float* vnt_old  = (const float*)d_in[2];
    const float* ksum_old = (const float*)d_in[3];
    const int*   kcnt_old = (const int*)d_in[4];
    const float* vnb_old  = (const float*)d_in[5];
    const int*   pos      = (const int*)d_in[6];
    const float* kb       = (const float*)d_in[7];
    const float* vb       = (const float*)d_in[8];
    const float* vnorm    = (const float*)d_in[9];
    float* out = (float*)d_out;

    k_main<<<Bc * TBc, 1024, 0, stream>>>(kc_old, vc_old, vnt_old, ksum_old,
                                          kcnt_old, vnb_old, kb, vb, vnorm,
                                          pos, out);
}